// Round 1
// baseline (487.922 us; speedup 1.0000x reference)
//
#include <hip/hip_runtime.h>
#include <math.h>

#define N_ROWS 16384
#define DMODEL 1024
#define DFF    4096

typedef _Float16 f16;
typedef __attribute__((ext_vector_type(4))) _Float16 f16x4;
typedef __attribute__((ext_vector_type(8))) _Float16 f16x8;
typedef __attribute__((ext_vector_type(4))) float f32x4;

// Async global->LDS copy, 16B per lane. LDS dest must be wave-uniform base +
// lane*16 (it is: we pass base + tid*16, contiguous in lane order).
__device__ inline void async_ld16(const f16* g, f16* l) {
  __builtin_amdgcn_global_load_lds(
      (__attribute__((address_space(1))) void*)(g),
      (__attribute__((address_space(3))) void*)(l),
      16, 0, 0);
}

// fp32 -> fp16 cast, 8 elems/thread, n divisible by 2048
__global__ void cast_to_f16(const float* __restrict__ src, f16* __restrict__ dst, int n) {
  int i = (blockIdx.x * blockDim.x + threadIdx.x) * 8;
  if (i >= n) return;
  float4 v0 = ((const float4*)(src + i))[0];
  float4 v1 = ((const float4*)(src + i))[1];
  f16x8 h = { (f16)v0.x, (f16)v0.y, (f16)v0.z, (f16)v0.w,
              (f16)v1.x, (f16)v1.y, (f16)v1.z, (f16)v1.w };
  *(f16x8*)(dst + i) = h;
}

// C[M,Nc] = tanh(A[M,K] @ B[Nc,K]^T + bias), A/B f16 (K contiguous), fp32 acc.
// m97 structure: 128x128 tile, BK=32, 4 waves 2x2, 4x4 16x16x32 MFMA per wave,
// global_load_lds width=16 staging, 2-barrier K-loop.
template <int K, typename OUT_T>
__global__ __launch_bounds__(256, 3)
void gemm_bt_tanh(const f16* __restrict__ A, const f16* __restrict__ B,
                  const float* __restrict__ bias, OUT_T* __restrict__ C, int Nc) {
  __shared__ __align__(16) f16 As[128 * 32];
  __shared__ __align__(16) f16 Bs[128 * 32];

  const int tid  = threadIdx.x;
  const int lane = tid & 63;
  const int wave = tid >> 6;
  const size_t row0 = (size_t)blockIdx.x * 128;
  const size_t col0 = (size_t)blockIdx.y * 128;
  const int wm = (wave >> 1) * 64;  // wave sub-tile origin (rows)
  const int wn = (wave & 1) * 64;   // wave sub-tile origin (cols)
  const int fr = lane & 15;         // row/col within 16-tile
  const int fk = (lane >> 4) * 8;   // k offset within 32-chunk

  // staging: thread t loads row t/4, 16B chunk t%4 (rows 0-63; +64*K for 64-127)
  const int srow   = tid >> 2;
  const int schunk = (tid & 3) * 8;
  const f16* Ap = A + (row0 + srow) * (size_t)K + schunk;
  const f16* Bp = B + (col0 + srow) * (size_t)K + schunk;
  f16* Asd = As + tid * 8;
  f16* Bsd = Bs + tid * 8;

  f32x4 acc[4][4] = {};

  for (int k0 = 0; k0 < K; k0 += 32) {
    __syncthreads();  // all waves done reading LDS from previous iter
    async_ld16(Ap + k0, Asd);
    async_ld16(Ap + (size_t)64 * K + k0, Asd + 2048);
    async_ld16(Bp + k0, Bsd);
    async_ld16(Bp + (size_t)64 * K + k0, Bsd + 2048);
    __syncthreads();  // drains vmcnt(0): staged tiles visible

    f16x8 af[4], bf[4];
#pragma unroll
    for (int i = 0; i < 4; ++i) {
      af[i] = *(const f16x8*)(As + (wm + i * 16 + fr) * 32 + fk);
      bf[i] = *(const f16x8*)(Bs + (wn + i * 16 + fr) * 32 + fk);
    }
#pragma unroll
    for (int i = 0; i < 4; ++i)
#pragma unroll
      for (int j = 0; j < 4; ++j)
        acc[i][j] = __builtin_amdgcn_mfma_f32_16x16x32_f16(af[i], bf[j], acc[i][j], 0, 0, 0);
  }

  // epilogue: C/D map col=lane&15, row=(lane>>4)*4+reg  [m89-verified]
  const int erow = wm + (lane >> 4) * 4;
  const int ecol = wn + fr;
#pragma unroll
  for (int i = 0; i < 4; ++i) {
#pragma unroll
    for (int j = 0; j < 4; ++j) {
      size_t gcol = col0 + ecol + j * 16;
      float b = bias[gcol];
#pragma unroll
      for (int r = 0; r < 4; ++r) {
        size_t grow = row0 + erow + i * 16 + r;
        C[grow * (size_t)Nc + gcol] = (OUT_T)tanhf(acc[i][j][r] + b);
      }
    }
  }
}

// out[row] = sigmoid(sum_k wx[row][k] * batch[row][k]); 256 thr/row, fp32 acc
__global__ void rowdot_sigmoid(const f16* __restrict__ wx, const float* __restrict__ batch,
                               float* __restrict__ out) {
  const int row = blockIdx.x;
  const int t = threadIdx.x;
  const f16* wr = wx + (size_t)row * DMODEL + t * 4;
  const float* br = batch + (size_t)row * DMODEL + t * 4;
  f16x4 h = *(const f16x4*)wr;
  float4 b4 = *(const float4*)br;
  float s = (float)h[0] * b4.x + (float)h[1] * b4.y + (float)h[2] * b4.z + (float)h[3] * b4.w;
#pragma unroll
  for (int off = 32; off > 0; off >>= 1) s += __shfl_down(s, off, 64);
  __shared__ float partial[4];
  if ((t & 63) == 0) partial[t >> 6] = s;
  __syncthreads();
  if (t == 0) {
    float tot = partial[0] + partial[1] + partial[2] + partial[3];
    out[row] = 1.0f / (1.0f + expf(-tot));
  }
}

extern "C" void kernel_launch(void* const* d_in, const int* in_sizes, int n_in,
                              void* d_out, int out_size, void* d_ws, size_t ws_size,
                              hipStream_t stream) {
  const float* batch = (const float*)d_in[0];
  const float* W1    = (const float*)d_in[1];
  const float* b1    = (const float*)d_in[2];
  const float* W2    = (const float*)d_in[3];
  const float* b2    = (const float*)d_in[4];
  float* out = (float*)d_out;

  char* ws = (char*)d_ws;
  f16* batch_h = (f16*)ws;  ws += (size_t)N_ROWS * DMODEL * sizeof(f16);  //  32 MB
  f16* W1_h    = (f16*)ws;  ws += (size_t)DFF * DMODEL * sizeof(f16);     //   8 MB
  f16* W2_h    = (f16*)ws;  ws += (size_t)DMODEL * DFF * sizeof(f16);     //   8 MB
  f16* inner_h = (f16*)ws;  ws += (size_t)N_ROWS * DFF * sizeof(f16);     // 128 MB
  f16* wx_h    = (f16*)ws;  ws += (size_t)N_ROWS * DMODEL * sizeof(f16);  //  32 MB
  // total 208 MB

  const int nb  = N_ROWS * DMODEL;   // 16.7M, /2048 = 8192
  const int nw  = DFF * DMODEL;      //  4.2M, /2048 = 2048
  cast_to_f16<<<nb / 2048, 256, 0, stream>>>(batch, batch_h, nb);
  cast_to_f16<<<nw / 2048, 256, 0, stream>>>(W1, W1_h, nw);
  cast_to_f16<<<nw / 2048, 256, 0, stream>>>(W2, W2_h, nw);

  dim3 g1(N_ROWS / 128, DFF / 128);     // (128, 32)
  gemm_bt_tanh<DMODEL, f16><<<g1, 256, 0, stream>>>(batch_h, W1_h, b1, inner_h, DFF);
  dim3 g2(N_ROWS / 128, DMODEL / 128);  // (128, 8)
  gemm_bt_tanh<DFF, f16><<<g2, 256, 0, stream>>>(inner_h, W2_h, b2, wx_h, DMODEL);

  rowdot_sigmoid<<<N_ROWS, 256, 0, stream>>>(wx_h, batch, out);
}